// Round 1
// baseline (4877.677 us; speedup 1.0000x reference)
//
#include <hip/hip_runtime.h>
#include <hip/hip_bf16.h>
#include <cstdint>

#define NB 16          // batch
#define NC 32          // residual channels
#define T0 16384       // input length
#define NL 30          // layers
#define SKC 256        // skip channels
#define TF 13315       // final time length
#define TFP 13376      // padded z-stack row stride (multiple of 64)

typedef __hip_bfloat16 bf16;

__device__ __forceinline__ float bflo(uint32_t u){ return __uint_as_float(u << 16); }
__device__ __forceinline__ float bfhi(uint32_t u){ return __uint_as_float(u & 0xffff0000u); }

// ---------------- prep: transpose weights into [k][c] layouts ----------------
__global__ __launch_bounds__(256) void prep_kernel(
    const float* __restrict__ skip_w, const float* __restrict__ e1w,
    const float* __restrict__ e2w, float* __restrict__ wt_skip,
    float* __restrict__ e1t, float* __restrict__ e2t){
  int idx = blockIdx.x*256 + threadIdx.x;
  if (idx < NL*NC*SKC){
    // wt_skip[(i*32+ci)*256 + c] = skip_w[i][c][ci]
    int c = idx & 255, k = idx >> 8;
    int i = k >> 5, ci = k & 31;
    wt_skip[idx] = skip_w[((size_t)i*SKC + c)*NC + ci];
  } else {
    int j = idx - NL*NC*SKC;
    if (j < SKC*SKC){
      int c = j & 255, k = j >> 8;
      e1t[j] = e1w[(size_t)c*SKC + k];   // e1t[k*256+c] = end1_w[c][k]
      e2t[j] = e2w[(size_t)c*SKC + k];
    }
  }
}

// ---------------- causal 1x1 conv: y[16,1,T] -> x0[16,32,T] ----------------
__global__ __launch_bounds__(256) void causal_kernel(
    const float* __restrict__ y, const float* __restrict__ cw,
    const float* __restrict__ cb, float* __restrict__ x0){
  int idx = blockIdx.x*256 + threadIdx.x;
  if (idx >= NB*T0) return;
  int b = idx >> 14, t = idx & (T0-1);
  float yv = y[idx];
  #pragma unroll
  for (int c = 0; c < NC; c++)
    x0[((size_t)b*NC + c)*T0 + t] = cw[c]*yv + cb[c];
}

// ---------------- fused dilated layer: filt/gate conv + gate + res ----------
// x_{i+1}[c,t] = res_w @ z + x_i[c, t+d];  z trimmed (last TF) -> zout (bf16)
__global__ __launch_bounds__(256) void layer_kernel(
    const float* __restrict__ xin, float* __restrict__ xout,
    bf16* __restrict__ zout,
    const float* __restrict__ fw, const float* __restrict__ gw,
    const float* __restrict__ rw,
    int Tin, int Tout, int d, int trim){
  int t = blockIdx.x*256 + threadIdx.x;
  int b = blockIdx.y;
  if (t >= Tout) return;
  const float* xb = xin + (size_t)b*NC*Tin;
  float x0[NC], x1[NC], xacc[NC];
  #pragma unroll
  for (int c = 0; c < NC; c++){
    x0[c] = xb[(size_t)c*Tin + t];
    x1[c] = xb[(size_t)c*Tin + t + d];
    xacc[c] = x1[c];                       // residual
  }
  bf16* zb = zout + (size_t)b*NC*TFP + (t - trim);
  for (int co = 0; co < NC; co++){         // runtime loop: keeps I-footprint small
    float f = 0.f, g = 0.f;
    const float* fwr = fw + co*64;
    const float* gwr = gw + co*64;
    #pragma unroll
    for (int ci = 0; ci < NC; ci++){
      f = fmaf(fwr[ci*2+0], x0[ci], f);
      f = fmaf(fwr[ci*2+1], x1[ci], f);
      g = fmaf(gwr[ci*2+0], x0[ci], g);
      g = fmaf(gwr[ci*2+1], x1[ci], g);
    }
    f = fminf(fmaxf(f, -30.f), 30.f);
    g = fminf(fmaxf(g, -30.f), 30.f);
    float ef = __expf(-2.f*f);
    float z = ((1.f - ef)/(1.f + ef)) * (1.f/(1.f + __expf(-g)));
    if (t >= trim) zb[(size_t)co*TFP] = __float2bfloat16(z);
    #pragma unroll
    for (int c = 0; c < NC; c++)
      xacc[c] = fmaf(rw[c*NC + co], z, xacc[c]);   // res as outer-product accum
  }
  float* xo = xout + (size_t)b*NC*Tout + t;
  #pragma unroll
  for (int c = 0; c < NC; c++) xo[(size_t)c*Tout] = xacc[c];
}

// ---------------- skip GEMM: out[b,c,t] (+)= sum_k wt[k][c] * z[k][b][t] ----
// block: 256 threads, tile 256c x 64t. zl staged fp32 in 64-k subchunks.
__global__ __launch_bounds__(256) void skip_gemm_kernel(
    const bf16* __restrict__ zstack,   // [Lc][NB][NC][TFP]
    const float* __restrict__ wt,      // [960][256]
    float* __restrict__ out,           // [NB][256][TF]
    int nk, int l0, int accumulate){
  __shared__ float zl[64*68];
  int tid = threadIdx.x;
  int b = blockIdx.y;
  int t0 = blockIdx.x*64;
  int cq = tid & 63;       // c = cq*4 + i
  int tg = tid >> 6;       // t = t0 + tg*16 + j
  float acc[4][16];
  #pragma unroll
  for (int i = 0; i < 4; i++)
    #pragma unroll
    for (int j = 0; j < 16; j++) acc[i][j] = 0.f;

  for (int ks = 0; ks < nk; ks += 64){
    int kmax = nk - ks; if (kmax > 64) kmax = 64;
    __syncthreads();
    {
      int r = tid >> 2;                 // k-row 0..63
      int toff = (tid & 3) << 4;        // 16 bf16 per thread
      if (r < kmax){
        int kg = ks + r;
        int lz = kg >> 5, ci = kg & 31;
        const uint4* zp = (const uint4*)(zstack +
            ((((size_t)lz*NB + b)*NC + ci)*TFP + t0 + toff));
        uint4 u0 = zp[0], u1 = zp[1];
        float* dst = &zl[r*68 + toff];
        dst[0]=bflo(u0.x); dst[1]=bfhi(u0.x); dst[2]=bflo(u0.y); dst[3]=bfhi(u0.y);
        dst[4]=bflo(u0.z); dst[5]=bfhi(u0.z); dst[6]=bflo(u0.w); dst[7]=bfhi(u0.w);
        dst[8]=bflo(u1.x); dst[9]=bfhi(u1.x); dst[10]=bflo(u1.y); dst[11]=bfhi(u1.y);
        dst[12]=bflo(u1.z); dst[13]=bfhi(u1.z); dst[14]=bflo(u1.w); dst[15]=bfhi(u1.w);
      }
    }
    __syncthreads();
    for (int kk = 0; kk < kmax; kk++){
      float4 w4 = *(const float4*)(wt + (((size_t)(l0*32 + ks + kk)) << 8) + (cq << 2));
      float wv[4] = {w4.x, w4.y, w4.z, w4.w};
      const float* zr = &zl[kk*68 + (tg << 4)];
      #pragma unroll
      for (int j4 = 0; j4 < 4; j4++){
        float4 zv = *(const float4*)(zr + (j4 << 2));
        float za[4] = {zv.x, zv.y, zv.z, zv.w};
        #pragma unroll
        for (int i = 0; i < 4; i++)
          #pragma unroll
          for (int l = 0; l < 4; l++)
            acc[i][j4*4 + l] = fmaf(wv[i], za[l], acc[i][j4*4 + l]);
      }
    }
  }
  // store / accumulate
  #pragma unroll
  for (int i = 0; i < 4; i++){
    int c = (cq << 2) + i;
    float* orow = out + ((size_t)b*SKC + c)*TF + t0 + (tg << 4);
    #pragma unroll
    for (int j = 0; j < 16; j++){
      int tt = t0 + (tg << 4) + j;
      if (tt < TF){
        if (accumulate) orow[j] += acc[i][j];
        else            orow[j]  = acc[i][j];
      }
    }
  }
}

// ---------------- end: in-place relu -> end1 -> relu -> end2 ----------------
__global__ __launch_bounds__(256) void end_kernel(
    float* __restrict__ io,
    const float* __restrict__ e1t, const float* __restrict__ b1,
    const float* __restrict__ e2t, const float* __restrict__ b2){
  __shared__ float sl[256*36];   // reused for input then hidden
  int tid = threadIdx.x;
  int b = blockIdx.y;
  int t0 = blockIdx.x*32;
  // stage relu(skip) tile [256][32]
  for (int it = 0; it < 32; it++){
    int f = it*256 + tid;
    int row = f >> 5, col = f & 31;
    int tt = t0 + col;
    float v = (tt < TF) ? io[((size_t)b*SKC + row)*TF + tt] : 0.f;
    sl[row*36 + col] = fmaxf(v, 0.f);
  }
  __syncthreads();
  int cq = tid & 63, tg = tid >> 6;   // c = cq*4+i, t = t0 + tg*8 + j
  float acc[4][8];
  #pragma unroll
  for (int i = 0; i < 4; i++)
    #pragma unroll
    for (int j = 0; j < 8; j++) acc[i][j] = 0.f;
  for (int k = 0; k < 256; k++){
    float4 w4 = *(const float4*)(e1t + ((size_t)k << 8) + (cq << 2));
    float wv[4] = {w4.x, w4.y, w4.z, w4.w};
    const float* zr = &sl[k*36 + (tg << 3)];
    float4 z0 = *(const float4*)(zr);
    float4 z1 = *(const float4*)(zr + 4);
    float za[8] = {z0.x, z0.y, z0.z, z0.w, z1.x, z1.y, z1.z, z1.w};
    #pragma unroll
    for (int i = 0; i < 4; i++)
      #pragma unroll
      for (int j = 0; j < 8; j++)
        acc[i][j] = fmaf(wv[i], za[j], acc[i][j]);
  }
  __syncthreads();   // done reading sl
  #pragma unroll
  for (int i = 0; i < 4; i++){
    float bias = b1[(cq << 2) + i];
    #pragma unroll
    for (int j = 0; j < 8; j++)
      sl[((cq << 2) + i)*36 + (tg << 3) + j] = fmaxf(acc[i][j] + bias, 0.f);
  }
  __syncthreads();
  #pragma unroll
  for (int i = 0; i < 4; i++)
    #pragma unroll
    for (int j = 0; j < 8; j++) acc[i][j] = 0.f;
  for (int k = 0; k < 256; k++){
    float4 w4 = *(const float4*)(e2t + ((size_t)k << 8) + (cq << 2));
    float wv[4] = {w4.x, w4.y, w4.z, w4.w};
    const float* zr = &sl[k*36 + (tg << 3)];
    float4 z0 = *(const float4*)(zr);
    float4 z1 = *(const float4*)(zr + 4);
    float za[8] = {z0.x, z0.y, z0.z, z0.w, z1.x, z1.y, z1.z, z1.w};
    #pragma unroll
    for (int i = 0; i < 4; i++)
      #pragma unroll
      for (int j = 0; j < 8; j++)
        acc[i][j] = fmaf(wv[i], za[j], acc[i][j]);
  }
  #pragma unroll
  for (int i = 0; i < 4; i++){
    int c = (cq << 2) + i;
    float bias = b2[c];
    #pragma unroll
    for (int j = 0; j < 8; j++){
      int tt = t0 + (tg << 3) + j;
      if (tt < TF) io[((size_t)b*SKC + c)*TF + tt] = acc[i][j] + bias;
    }
  }
}

extern "C" void kernel_launch(void* const* d_in, const int* in_sizes, int n_in,
                              void* d_out, int out_size, void* d_ws, size_t ws_size,
                              hipStream_t stream) {
  (void)in_sizes; (void)n_in; (void)out_size;
  const float* y   = (const float*)d_in[0];
  const float* cw  = (const float*)d_in[1];
  const float* cb  = (const float*)d_in[2];
  const float* fw  = (const float*)d_in[3];
  const float* gw  = (const float*)d_in[4];
  const float* rw  = (const float*)d_in[5];
  const float* sw  = (const float*)d_in[6];
  const float* e1w = (const float*)d_in[7];
  const float* e1b = (const float*)d_in[8];
  const float* e2w = (const float*)d_in[9];
  const float* e2b = (const float*)d_in[10];
  float* out = (float*)d_out;
  char* ws = (char*)d_ws;

  const size_t XB = (size_t)NB*NC*T0*4;          // 33,554,432
  float* xb0     = (float*)(ws);
  float* xb1     = (float*)(ws + XB);
  float* wt_skip = (float*)(ws + 2*XB);
  float* e1t     = (float*)(ws + 2*XB + 983040);
  float* e2t     = (float*)(ws + 2*XB + 983040 + 262144);
  size_t zoff    = 2*XB + 983040 + 2*262144;
  bf16*  zstack  = (bf16*)(ws + zoff);
  const size_t ZPL = (size_t)NB*NC*TFP*2;        // bytes per layer in z-stack

  int L = 1;
  if (ws_size > zoff + ZPL){
    size_t cap = (ws_size - zoff) / ZPL;
    L = cap > 30 ? 30 : (int)cap;
    if (L < 1) L = 1;
  }

  prep_kernel<<<dim3((NL*NC*SKC + SKC*SKC + 255)/256), 256, 0, stream>>>(
      sw, e1w, e2w, wt_skip, e1t, e2t);
  causal_kernel<<<dim3((NB*T0 + 255)/256), 256, 0, stream>>>(y, cw, cb, xb0);

  float* xin = xb0; float* xout = xb1;
  int Ti = T0;
  int chunkStart = 0;
  while (chunkStart < NL){
    int Lc = NL - chunkStart; if (Lc > L) Lc = L;
    for (int j = 0; j < Lc; j++){
      int i = chunkStart + j;
      int d = 1 << (i % 10);
      int Tout = Ti - d;
      layer_kernel<<<dim3((Tout + 255)/256, NB), 256, 0, stream>>>(
          xin, xout, zstack + (size_t)j*NB*NC*TFP,
          fw + (size_t)i*2048, gw + (size_t)i*2048, rw + (size_t)i*1024,
          Ti, Tout, d, Tout - TF);
      float* tmp = xin; xin = xout; xout = tmp;
      Ti = Tout;
    }
    skip_gemm_kernel<<<dim3((TF + 63)/64, NB), 256, 0, stream>>>(
        zstack, wt_skip, out, Lc*32, chunkStart, chunkStart > 0 ? 1 : 0);
    chunkStart += Lc;
  }
  end_kernel<<<dim3((TF + 31)/32, NB), 256, 0, stream>>>(out, e1t, e1b, e2t, e2b);
}

// Round 2
// 3633.975 us; speedup vs baseline: 1.3422x; 1.3422x over previous
//
#include <hip/hip_runtime.h>
#include <hip/hip_bf16.h>
#include <cstdint>

#define NB 16
#define NC 32
#define T0 16384
#define NL 30
#define SKC 256
#define TF 13315
#define TFP 13376

typedef _Float16 f16;
typedef _Float16 f16x2 __attribute__((ext_vector_type(2)));
typedef _Float16 f16x8 __attribute__((ext_vector_type(8)));
typedef float f32x4 __attribute__((ext_vector_type(4)));

#define MFMA16(a,b,c) __builtin_amdgcn_mfma_f32_16x16x32_f16(a,b,c,0,0,0)

__device__ __forceinline__ float fdot2c(uint32_t w, uint32_t x, float c){
#if __has_builtin(__builtin_amdgcn_fdot2)
  return __builtin_amdgcn_fdot2(__builtin_bit_cast(f16x2, w),
                                __builtin_bit_cast(f16x2, x), c, false);
#else
  f16x2 a = __builtin_bit_cast(f16x2, w), b = __builtin_bit_cast(f16x2, x);
  return c + (float)a.x*(float)b.x + (float)a.y*(float)b.y;
#endif
}

// ---------------- prep: weights -> f16 fragment order / dot2 pairs ----------
__global__ __launch_bounds__(256) void prep2(
    const float* __restrict__ sw, const float* __restrict__ e1w,
    const float* __restrict__ e2w, const float* __restrict__ fw,
    const float* __restrict__ gw, const float* __restrict__ rw,
    f16* __restrict__ wsk, f16* __restrict__ e1f, f16* __restrict__ e2f,
    uint32_t* __restrict__ fgp, uint32_t* __restrict__ ggp,
    uint32_t* __restrict__ rwp){
  int idx = blockIdx.x*256 + threadIdx.x;
  if (idx < 30720){                    // skip weights frag: [i][mt][lane][8]
    int lane = idx & 63, mt = (idx>>6)&15, i = idx>>10;
    int m = mt*16 + (lane&15);
    int kl = (lane>>4)*8;
    const float* s = sw + ((size_t)i*SKC + m)*NC + kl;
    f16* dp = wsk + (size_t)idx*8;
    #pragma unroll
    for (int j=0;j<8;j++) dp[j] = (f16)s[j];
  } else if (idx < 38912){             // e1 frag: [ks][mt][lane][8]
    int j2 = idx - 30720;
    int lane = j2&63, mt = (j2>>6)&15, ks = j2>>10;
    int m = mt*16 + (lane&15);
    int k = ks*32 + (lane>>4)*8;
    const float* s = e1w + (size_t)m*SKC + k;
    f16* dp = e1f + (size_t)j2*8;
    #pragma unroll
    for (int j=0;j<8;j++) dp[j] = (f16)s[j];
  } else if (idx < 47104){             // e2 frag
    int j2 = idx - 38912;
    int lane = j2&63, mt = (j2>>6)&15, ks = j2>>10;
    int m = mt*16 + (lane&15);
    int k = ks*32 + (lane>>4)*8;
    const float* s = e2w + (size_t)m*SKC + k;
    f16* dp = e2f + (size_t)j2*8;
    #pragma unroll
    for (int j=0;j<8;j++) dp[j] = (f16)s[j];
  } else if (idx < 77824){             // filt pairs: [i][co][ci] (2 taps)
    int j2 = idx - 47104;
    const float* s = fw + (size_t)j2*2;
    f16x2 p; p.x = (f16)s[0]; p.y = (f16)s[1];
    fgp[j2] = __builtin_bit_cast(uint32_t, p);
  } else if (idx < 108544){            // gate pairs
    int j2 = idx - 77824;
    const float* s = gw + (size_t)j2*2;
    f16x2 p; p.x = (f16)s[0]; p.y = (f16)s[1];
    ggp[j2] = __builtin_bit_cast(uint32_t, p);
  } else if (idx < 123904){            // res pairs: [i][c][j] = rw[i][c][2j..2j+1]
    int j2 = idx - 108544;
    int i = j2 >> 9, c = (j2>>4)&31, j = j2&15;
    const float* s = rw + ((size_t)i*NC + c)*NC + 2*j;
    f16x2 p; p.x = (f16)s[0]; p.y = (f16)s[1];
    rwp[j2] = __builtin_bit_cast(uint32_t, p);
  }
}

// ---------------- causal: y[16,1,T] -> x0[b][t][32] f16 ----------------
__global__ __launch_bounds__(256) void causal2(
    const float* __restrict__ y, const float* __restrict__ cw,
    const float* __restrict__ cb, f16* __restrict__ x0){
  int idx = blockIdx.x*256 + threadIdx.x;
  int b = idx >> 14, t = idx & (T0-1);
  float yv = y[idx];
  uint32_t wpk[16];
  #pragma unroll
  for (int j=0;j<16;j++){
    f16x2 p;
    p.x = (f16)(cw[2*j]*yv + cb[2*j]);
    p.y = (f16)(cw[2*j+1]*yv + cb[2*j+1]);
    wpk[j] = __builtin_bit_cast(uint32_t, p);
  }
  uint4* dst = (uint4*)(x0 + ((size_t)b*T0 + t)*NC);
  dst[0] = make_uint4(wpk[0],wpk[1],wpk[2],wpk[3]);
  dst[1] = make_uint4(wpk[4],wpk[5],wpk[6],wpk[7]);
  dst[2] = make_uint4(wpk[8],wpk[9],wpk[10],wpk[11]);
  dst[3] = make_uint4(wpk[12],wpk[13],wpk[14],wpk[15]);
}

// ---------------- fused dilated layer (fdot2), x layout [b][t][32] ----------
__global__ __launch_bounds__(256) void layer2(
    const f16* __restrict__ xin, f16* __restrict__ xout, f16* __restrict__ zl,
    const uint32_t* __restrict__ fgp, const uint32_t* __restrict__ ggp,
    const uint32_t* __restrict__ rwp,
    int Tin, int Tout, int d, int trim){
  int t = blockIdx.x*256 + threadIdx.x;
  int b = blockIdx.y;
  if (t >= Tout) return;
  const uint4* xa = (const uint4*)(xin + ((size_t)b*T0 + t)*NC);
  const uint4* xb = (const uint4*)(xin + ((size_t)b*T0 + t + d)*NC);
  uint4 A4[4], B4[4];
  #pragma unroll
  for (int q=0;q<4;q++){ A4[q] = xa[q]; B4[q] = xb[q]; }
  uint32_t Aw[16], Bw[16];
  #pragma unroll
  for (int q=0;q<4;q++){
    Aw[4*q+0]=A4[q].x; Aw[4*q+1]=A4[q].y; Aw[4*q+2]=A4[q].z; Aw[4*q+3]=A4[q].w;
    Bw[4*q+0]=B4[q].x; Bw[4*q+1]=B4[q].y; Bw[4*q+2]=B4[q].z; Bw[4*q+3]=B4[q].w;
  }
  uint32_t xp[32]; float x1f[32];
  #pragma unroll
  for (int wd=0; wd<16; wd++){
    uint32_t a = Aw[wd], bb = Bw[wd];
    xp[2*wd]   = (a & 0xffffu) | (bb << 16);
    xp[2*wd+1] = (a >> 16) | (bb & 0xffff0000u);
    f16x2 bh = __builtin_bit_cast(f16x2, bb);
    x1f[2*wd] = (float)bh.x; x1f[2*wd+1] = (float)bh.y;
  }
  float z[32];
  #pragma unroll
  for (int co=0; co<32; co++){
    const uint32_t* fp = fgp + co*32;
    const uint32_t* gp = ggp + co*32;
    float f = 0.f, g = 0.f;
    #pragma unroll
    for (int ci=0; ci<32; ci++){
      f = fdot2c(fp[ci], xp[ci], f);
      g = fdot2c(gp[ci], xp[ci], g);
    }
    f = fminf(fmaxf(f, -30.f), 30.f);
    g = fminf(fmaxf(g, -30.f), 30.f);
    float ef = __expf(-2.f*f);
    z[co] = ((1.f - ef)/(1.f + ef)) * (1.f/(1.f + __expf(-g)));
  }
  uint32_t zp[16];
  #pragma unroll
  for (int j=0;j<16;j++){
    f16x2 p; p.x = (f16)z[2*j]; p.y = (f16)z[2*j+1];
    zp[j] = __builtin_bit_cast(uint32_t, p);
  }
  if (t >= trim){
    uint4* zo = (uint4*)(zl + ((size_t)b*TFP + (t - trim))*NC);
    zo[0] = make_uint4(zp[0],zp[1],zp[2],zp[3]);
    zo[1] = make_uint4(zp[4],zp[5],zp[6],zp[7]);
    zo[2] = make_uint4(zp[8],zp[9],zp[10],zp[11]);
    zo[3] = make_uint4(zp[12],zp[13],zp[14],zp[15]);
  }
  uint32_t xo[16];
  #pragma unroll
  for (int j=0;j<16;j++){
    float a0 = x1f[2*j], a1 = x1f[2*j+1];
    const uint32_t* r0 = rwp + (2*j)*16;
    const uint32_t* r1 = rwp + (2*j+1)*16;
    #pragma unroll
    for (int k=0;k<16;k++){
      a0 = fdot2c(r0[k], zp[k], a0);
      a1 = fdot2c(r1[k], zp[k], a1);
    }
    f16x2 p; p.x = (f16)a0; p.y = (f16)a1;
    xo[j] = __builtin_bit_cast(uint32_t, p);
  }
  uint4* xod = (uint4*)(xout + ((size_t)b*T0 + t)*NC);
  xod[0] = make_uint4(xo[0],xo[1],xo[2],xo[3]);
  xod[1] = make_uint4(xo[4],xo[5],xo[6],xo[7]);
  xod[2] = make_uint4(xo[8],xo[9],xo[10],xo[11]);
  xod[3] = make_uint4(xo[12],xo[13],xo[14],xo[15]);
}

// ---------------- skip GEMM (MFMA): out[b][c][t] (+)= W z ----------------
__global__ __launch_bounds__(256) void skip_mfma(
    const f16* __restrict__ zstack, const f16* __restrict__ wfrag,
    float* __restrict__ out, int L, int l0, int accumulate){
  __shared__ f16 zf[6*2048];   // [l][w4][64 slots][8] swizzled
  int tid = threadIdx.x;
  int b = blockIdx.y;
  int t0 = blockIdx.x*64;
  for (int l=0; l<L; l++){
    int t = tid >> 2, ch = tid & 3;
    const uint4* src = (const uint4*)(zstack +
        (((size_t)l*NB + b)*TFP + t0 + t)*NC + ch*8);
    uint4 v = *src;
    int lp = (t & 15) | (ch << 4);
    int si = lp ^ ch;
    *(uint4*)&zf[((size_t)((l*4) + (t>>4))*64 + si)*8] = v;
  }
  __syncthreads();
  int w = tid >> 6, lane = tid & 63;
  int rl = lane ^ ((lane >> 4) & 3);
  f32x4 acc[16];
  #pragma unroll
  for (int mt=0; mt<16; mt++) acc[mt] = f32x4{0.f,0.f,0.f,0.f};
  for (int l=0; l<L; l++){
    f16x8 bf = *(const f16x8*)&zf[((size_t)(l*4 + w)*64 + rl)*8];
    const f16x8* wp = (const f16x8*)wfrag + ((size_t)(l0 + l)*16)*64 + lane;
    #pragma unroll
    for (int mt=0; mt<16; mt++)
      acc[mt] = MFMA16(wp[mt*64], bf, acc[mt]);
  }
  int tt = t0 + w*16 + (lane & 15);
  if (tt < TF){
    int rq = (lane >> 4)*4;
    #pragma unroll
    for (int mt=0; mt<16; mt++){
      float* p = out + ((size_t)b*SKC + mt*16 + rq)*TF + tt;
      #pragma unroll
      for (int r=0;r<4;r++){
        float v = acc[mt][r];
        if (accumulate) v += p[(size_t)r*TF];
        p[(size_t)r*TF] = v;
      }
    }
  }
}

// ---------------- end: relu -> e1 -> relu -> e2 (MFMA, in-place) ------------
__global__ __launch_bounds__(256) void end_mfma(
    float* __restrict__ io, const f16* __restrict__ e1f,
    const float* __restrict__ b1, const f16* __restrict__ e2f,
    const float* __restrict__ b2){
  __shared__ f16 sA[64*264];
  __shared__ f16 sB[64*264];
  int tid = threadIdx.x, b = blockIdx.y, t0 = blockIdx.x*64;
  {
    int c = tid;
    const float* src = io + ((size_t)b*SKC + c)*TF + t0;
    if (t0 + 64 <= TF){
      #pragma unroll
      for (int j4=0;j4<16;j4++){
        float4 v = *(const float4*)(src + j4*4);
        sA[(j4*4+0)*264 + c] = (f16)fmaxf(v.x,0.f);
        sA[(j4*4+1)*264 + c] = (f16)fmaxf(v.y,0.f);
        sA[(j4*4+2)*264 + c] = (f16)fmaxf(v.z,0.f);
        sA[(j4*4+3)*264 + c] = (f16)fmaxf(v.w,0.f);
      }
    } else {
      for (int j=0;j<64;j++){
        float v = (t0+j < TF) ? src[j] : 0.f;
        sA[j*264 + c] = (f16)fmaxf(v,0.f);
      }
    }
  }
  __syncthreads();
  int w = tid>>6, lane = tid&63;
  int tl = w*16 + (lane&15);
  int kq = (lane>>4)*8;
  int rq = (lane>>4)*4;
  f32x4 acc[16];
  #pragma unroll
  for (int mt=0; mt<16; mt++) acc[mt] = f32x4{0.f,0.f,0.f,0.f};
  #pragma unroll
  for (int ks=0; ks<8; ks++){
    f16x8 bf = *(const f16x8*)&sA[(size_t)tl*264 + ks*32 + kq];
    const f16x8* wp = (const f16x8*)e1f + (size_t)(ks*16)*64 + lane;
    #pragma unroll
    for (int mt=0; mt<16; mt++)
      acc[mt] = MFMA16(wp[mt*64], bf, acc[mt]);
  }
  #pragma unroll
  for (int mt=0; mt<16; mt++){
    #pragma unroll
    for (int r=0;r<4;r++){
      int c = mt*16 + rq + r;
      sB[(size_t)tl*264 + c] = (f16)fmaxf(acc[mt][r] + b1[c], 0.f);
    }
  }
  __syncthreads();
  #pragma unroll
  for (int mt=0; mt<16; mt++) acc[mt] = f32x4{0.f,0.f,0.f,0.f};
  #pragma unroll
  for (int ks=0; ks<8; ks++){
    f16x8 bf = *(const f16x8*)&sB[(size_t)tl*264 + ks*32 + kq];
    const f16x8* wp = (const f16x8*)e2f + (size_t)(ks*16)*64 + lane;
    #pragma unroll
    for (int mt=0; mt<16; mt++)
      acc[mt] = MFMA16(wp[mt*64], bf, acc[mt]);
  }
  int tt = t0 + tl;
  if (tt < TF){
    #pragma unroll
    for (int mt=0; mt<16; mt++){
      #pragma unroll
      for (int r=0;r<4;r++){
        int c = mt*16 + rq + r;
        io[((size_t)b*SKC + c)*TF + tt] = acc[mt][r] + b2[c];
      }
    }
  }
}

extern "C" void kernel_launch(void* const* d_in, const int* in_sizes, int n_in,
                              void* d_out, int out_size, void* d_ws, size_t ws_size,
                              hipStream_t stream) {
  (void)in_sizes; (void)n_in; (void)out_size;
  const float* y   = (const float*)d_in[0];
  const float* cw  = (const float*)d_in[1];
  const float* cb  = (const float*)d_in[2];
  const float* fw  = (const float*)d_in[3];
  const float* gw  = (const float*)d_in[4];
  const float* rw  = (const float*)d_in[5];
  const float* sw  = (const float*)d_in[6];
  const float* e1w = (const float*)d_in[7];
  const float* e1b = (const float*)d_in[8];
  const float* e2w = (const float*)d_in[9];
  const float* e2b = (const float*)d_in[10];
  float* out = (float*)d_out;
  char* ws = (char*)d_ws;

  f16* x0 = (f16*)ws;
  f16* x1 = (f16*)(ws + 16777216);
  f16* wsk = (f16*)(ws + 33554432);
  f16* e1f = (f16*)(ws + 34045952);
  f16* e2f = (f16*)(ws + 34177024);
  uint32_t* fgp = (uint32_t*)(ws + 34308096);
  uint32_t* ggp = (uint32_t*)(ws + 34430976);
  uint32_t* rwp = (uint32_t*)(ws + 34553856);
  f16* zstack = (f16*)(ws + 34615296);
  const size_t ZPLh = (size_t)NB*TFP*NC;       // f16 per z layer

  int L = 1;
  if (ws_size > 34615296 + ZPLh*2){
    size_t cap = (ws_size - 34615296)/(ZPLh*2);
    L = (int)(cap > 6 ? 6 : cap);
    if (L < 1) L = 1;
  }

  prep2<<<dim3(484), 256, 0, stream>>>(sw, e1w, e2w, fw, gw, rw,
                                       wsk, e1f, e2f, fgp, ggp, rwp);
  causal2<<<dim3(1024), 256, 0, stream>>>(y, cw, cb, x0);

  f16 *xi = x0, *xo = x1;
  int Ti = T0, cs = 0;
  while (cs < NL){
    int Lc = NL - cs; if (Lc > L) Lc = L;
    for (int j = 0; j < Lc; j++){
      int i = cs + j;
      int d = 1 << (i % 10);
      int Tout = Ti - d;
      layer2<<<dim3((Tout + 255)/256, NB), 256, 0, stream>>>(
          xi, xo, zstack + (size_t)j*ZPLh,
          fgp + (size_t)i*1024, ggp + (size_t)i*1024, rwp + (size_t)i*512,
          Ti, Tout, d, Tout - TF);
      f16* tmp = xi; xi = xo; xo = tmp;
      Ti = Tout;
    }
    skip_mfma<<<dim3(209, NB), 256, 0, stream>>>(zstack, wsk, out, Lc, cs, cs ? 1 : 0);
    cs += Lc;
  }
  end_mfma<<<dim3(209, NB), 256, 0, stream>>>(out, e1f, e1b, e2f, e2b);
}